// Round 8
// baseline (173.862 us; speedup 1.0000x reference)
//
#include <hip/hip_runtime.h>
#include <stdint.h>

#define S_LEN 2048
#define NHEADS 16
#define DHEAD 64
#define DMODEL 1024

typedef unsigned short u16;
typedef unsigned int u32;
typedef __bf16 bf16x8 __attribute__((ext_vector_type(8)));
typedef float f32x4 __attribute__((ext_vector_type(4)));
typedef float f32x16 __attribute__((ext_vector_type(16)));
typedef u32 u32x4 __attribute__((ext_vector_type(4)));
typedef u32 u32x2 __attribute__((ext_vector_type(2)));

__device__ __forceinline__ float bf2f(u16 u) {
  u32 x = ((u32)u) << 16;
  float f;
  __builtin_memcpy(&f, &x, 4);
  return f;
}
__device__ __forceinline__ u16 f2bf(float f) {
  u32 x;
  __builtin_memcpy(&x, &f, 4);
  x += 0x7FFFu + ((x >> 16) & 1u);
  return (u16)(x >> 16);
}
// packed f32 pair -> bf16 pair (lo = a, hi = b)
__device__ __forceinline__ u32 cvtpk(float a, float b) {
  u32 r;
  asm("v_cvt_pk_bf16_f32 %0, %1, %2" : "=v"(r) : "v"(a), "v"(b));
  return r;
}
// r[0] = {a_lo, b_lo}, r[1] = {a_hi, b_hi}
__device__ __forceinline__ u32x2 plswap2(u32 a, u32 b) {
  return __builtin_amdgcn_permlane32_swap(a, b, false, false);
}
// single-instruction exp2
__device__ __forceinline__ float fexp2(float x) {
  float r;
  asm("v_exp_f32 %0, %1" : "=v"(r) : "v"(x));
  return r;
}

#define AS1 __attribute__((address_space(1)))
#define AS3 __attribute__((address_space(3)))
__device__ __forceinline__ void gload16(const void* g, void* l) {
  __builtin_amdgcn_global_load_lds((AS1 void*)g, (AS3 void*)l, 16, 0, 0);
}

#define MFMA32(a, b, c) __builtin_amdgcn_mfma_f32_32x32x16_bf16(a, b, c, 0, 0, 0)

// ---------------- f32 -> bf16 convert: x (4 parts of 1M) + 4 weight mats ----
__global__ __launch_bounds__(256) void convert_k(
    const float* __restrict__ x, const float* __restrict__ wq, const float* __restrict__ wk,
    const float* __restrict__ wv, const float* __restrict__ wo,
    u16* __restrict__ xb, u16* __restrict__ wqb, u16* __restrict__ wkb,
    u16* __restrict__ wvb, u16* __restrict__ wob) {
  int part = blockIdx.y;
  const float* src;
  u16* dst;
  size_t base = 0;
  if (part < 4) { src = x; dst = xb; base = (size_t)part << 20; }
  else if (part == 4) { src = wq; dst = wqb; }
  else if (part == 5) { src = wk; dst = wkb; }
  else if (part == 6) { src = wv; dst = wvb; }
  else { src = wo; dst = wob; }
  size_t i = base + ((size_t)(blockIdx.x * 256 + threadIdx.x)) * 4;
  float4 v = *(const float4*)(src + i);
  ushort4 o;
  o.x = f2bf(v.x); o.y = f2bf(v.y); o.z = f2bf(v.z); o.w = f2bf(v.w);
  *(ushort4*)(dst + i) = o;
}

// ---------------- 128x128 bf16 GEMM, C = A * B^T (A:[M][K], B:[N][K]) ------
// MODE 0: write f32 row-major [M][N].
// MODE 1: z<2 -> bf16 [B,H,S,DK]; z==2 -> bf16 V^T [B,H,DK,S].
template <int MODE>
__global__ __launch_bounds__(256) void gemm128(
    const u16* __restrict__ A, const u16* __restrict__ B0, const u16* __restrict__ B1,
    const u16* __restrict__ B2, void* __restrict__ O0, void* __restrict__ O1,
    void* __restrict__ O2) {
  __shared__ alignas(16) u16 As[128 * 64];
  __shared__ alignas(16) u16 Bs[128 * 64];
  int z = blockIdx.z;
  const u16* Bm = (z == 0) ? B0 : ((z == 1) ? B1 : B2);
  void* Om = (z == 0) ? O0 : ((z == 1) ? O1 : O2);
  int m0 = blockIdx.x * 128, n0 = blockIdx.y * 128;
  int t = threadIdx.x;
  int w = t >> 6, lane = t & 63, lr = lane >> 4, lc = lane & 15;
  int wr = w >> 1, wc = w & 1;
  f32x4 acc[4][4] = {};
  int srow = t >> 3;
  int scolb = (t & 7) * 16;
  const char* Ag = (const char*)A;
  const char* Bg = (const char*)Bm;
  for (int k0 = 0; k0 < DMODEL; k0 += 64) {
#pragma unroll
    for (int i = 0; i < 4; i++) {
      gload16(Ag + ((size_t)(m0 + srow + i * 32) * DMODEL + k0) * 2 + scolb,
              (char*)As + i * 4096 + w * 1024);
      gload16(Bg + ((size_t)(n0 + srow + i * 32) * DMODEL + k0) * 2 + scolb,
              (char*)Bs + i * 4096 + w * 1024);
    }
    __syncthreads();
#pragma unroll
    for (int kk = 0; kk < 2; kk++) {
      bf16x8 af[4], bfr[4];
#pragma unroll
      for (int mi = 0; mi < 4; mi++)
        af[mi] = *(const bf16x8*)(As + (wr * 64 + mi * 16 + lc) * 64 + kk * 32 + lr * 8);
#pragma unroll
      for (int ni = 0; ni < 4; ni++)
        bfr[ni] = *(const bf16x8*)(Bs + (wc * 64 + ni * 16 + lc) * 64 + kk * 32 + lr * 8);
#pragma unroll
      for (int mi = 0; mi < 4; mi++)
#pragma unroll
        for (int ni = 0; ni < 4; ni++)
          acc[mi][ni] =
              __builtin_amdgcn_mfma_f32_16x16x32_bf16(af[mi], bfr[ni], acc[mi][ni], 0, 0, 0);
    }
    __syncthreads();
  }
  if constexpr (MODE == 0) {
    float* Of = (float*)Om;
#pragma unroll
    for (int mi = 0; mi < 4; mi++)
#pragma unroll
      for (int ni = 0; ni < 4; ni++) {
        int m = m0 + wr * 64 + mi * 16 + lr * 4;
        int n = n0 + wc * 64 + ni * 16 + lc;
#pragma unroll
        for (int r = 0; r < 4; r++) Of[(size_t)(m + r) * DMODEL + n] = acc[mi][ni][r];
      }
  } else {
    __shared__ alignas(16) u16 Epi[4][2560];  // per-wave 5120B scratch
    u16* Ew = Epi[w];
    int b = m0 >> 11;
    if (z != 2) {
      u16* Oh = (u16*)Om;
      int h = (n0 >> 6) + wc;
      int rr = lane >> 2, qq = lane & 3;
#pragma unroll
      for (int mi = 0; mi < 4; mi++) {
#pragma unroll
        for (int ni = 0; ni < 4; ni++)
#pragma unroll
          for (int r = 0; r < 4; r++)
            Ew[(lr * 4 + r) * 72 + ni * 16 + lc] = f2bf(acc[mi][ni][r]);
        asm volatile("s_waitcnt lgkmcnt(0)" ::: "memory");
        __builtin_amdgcn_sched_barrier(0);
        int s = (m0 + wr * 64 + mi * 16 + rr) & 2047;
        u16* dst = Oh + ((size_t)((b * NHEADS + h) * S_LEN + s)) * DHEAD + qq * 16;
        u32x4 c0 = *(const u32x4*)(Ew + rr * 72 + qq * 16);
        u32x4 c1 = *(const u32x4*)(Ew + rr * 72 + qq * 16 + 8);
        *(u32x4*)dst = c0;
        *(u32x4*)(dst + 8) = c1;
        __builtin_amdgcn_sched_barrier(0);
      }
    } else {
      u16* VTo = (u16*)Om;
      int bh = b * NHEADS + (n0 >> 6) + wc;
      int scol = (m0 & 2047) + wr * 64;
#pragma unroll
      for (int mi = 0; mi < 4; mi++) {
#pragma unroll
        for (int ni = 0; ni < 4; ni++) {
          int nloc = ni * 16 + lc;
#pragma unroll
          for (int k = 0; k < 2; k++) {
            u32 p = cvtpk(acc[mi][ni][2 * k], acc[mi][ni][2 * k + 1]);
            *(u32*)(Ew + nloc * 40 + lr * 4 + 2 * k) = p;
          }
        }
        asm volatile("s_waitcnt lgkmcnt(0)" ::: "memory");
        __builtin_amdgcn_sched_barrier(0);
        u32x4 c0 = *(const u32x4*)(Ew + lane * 40);
        u32x4 c1 = *(const u32x4*)(Ew + lane * 40 + 8);
        u16* dst = VTo + ((size_t)(bh * DHEAD + lane)) * S_LEN + scol + mi * 16;
        *(u32x4*)dst = c0;
        *(u32x4*)(dst + 8) = c1;
        __builtin_amdgcn_sched_barrier(0);
      }
    }
  }
}

// ---------------- RoPE in-place on bf16 Q (y=0, with 1/8 scale) and K (y=1) -
__global__ __launch_bounds__(256) void rope_k(u16* __restrict__ Q, u16* __restrict__ K,
                                              const int* __restrict__ pos) {
  int sel = blockIdx.y;
  u16* Aq = sel ? K : Q;
  float oscale = sel ? 1.0f : 0.125f;
  int idx = blockIdx.x * 256 + threadIdx.x;
  int r = idx >> 2, seg = idx & 3;
  int b = r >> 15, s = r & 2047;
  float p = (float)pos[(b << 11) + s];
  u16* ptr = Aq + (size_t)r * DHEAD + seg * 16;
  alignas(16) u16 e[16];
  *(uint4*)&e[0] = *(const uint4*)ptr;
  *(uint4*)&e[8] = *(const uint4*)(ptr + 8);
#pragma unroll
  for (int j = 0; j < 8; j++) {
    int i = seg * 8 + j;
    float fr = exp2f(-0.4152410118407687f * (float)i);
    float ang = p * fr;
    float sn, cs;
    __sincosf(ang, &sn, &cs);
    float ev = bf2f(e[2 * j]), ov = bf2f(e[2 * j + 1]);
    e[2 * j] = f2bf((ev * cs - ov * sn) * oscale);
    e[2 * j + 1] = f2bf((ev * sn + ov * cs) * oscale);
  }
  *(uint4*)ptr = *(const uint4*)&e[0];
  *(uint4*)(ptr + 8) = *(const uint4*)&e[8];
}

// ---------------- causal flash attention, v8: wave-flat, 8-tile chunks -----
// Chunk = up to 8 KV-tiles (512 kv). C(qt) = 1 + qt/16 chunks per q-tile ->
// 160 waves/bh, 5120 waves total (20/CU demand vs 16/CU VGPR cap) -> CUs
// stay full; max wave length 8 tiles -> short drain tail. Per-tile loads
// (v6 body: best measured); no prefetch (v5/v7 both regressed).
// y map (heavy qt first): y<64: qt=48+(y>>2),c=y&3; y<112: qt=32+(y-64)/3,
// c=(y-64)%3; y<144: qt=16+((y-112)>>1), c=(y-112)&1; else qt=y-144, c=0.
__global__ __launch_bounds__(64) void attn_k(const u16* __restrict__ Q,
                                             const u16* __restrict__ K,
                                             const u16* __restrict__ VT,
                                             u16* __restrict__ O,
                                             char* __restrict__ PB) {
  int bh = blockIdx.x;  // fast dim -> bh%8 tracks XCD
  int y = blockIdx.y;
  int qt, c;
  if (y < 64) { qt = 48 + (y >> 2); c = y & 3; }
  else if (y < 112) { int u = y - 64; qt = 32 + u / 3; c = u % 3; }
  else if (y < 144) { int u = y - 112; qt = 16 + (u >> 1); c = u & 1; }
  else { qt = y - 144; c = 0; }
  int ntd = qt >> 1;                  // diagonal tile
  int nt0 = c * 8;
  int nt1 = min(nt0 + 7, ntd);
  int C = 1 + (qt >> 4);              // chunks for this q-tile
  bool partial = (C > 1);
  int lane = threadIdx.x & 63;
  int ql = lane & 31, h = lane >> 5;
  size_t base = (size_t)bh * (S_LEN * DHEAD);
  int qrow = qt * 32 + ql;
  const u16* Kp = K + base + (size_t)ql * DHEAD + h * 8;
  const u16* Vp = VT + ((size_t)bh * DHEAD + ql) * S_LEN + h * 8;
  const u16* Qp = Q + base + (size_t)qrow * DHEAD + h * 8;
  bf16x8 qf[4];
#pragma unroll
  for (int kt = 0; kt < 4; kt++) qf[kt] = *(const bf16x8*)(Qp + kt * 16);
  f32x16 oacc[2] = {};
  float mrun = -1e30f, lrun = 0.0f;
  const float L2E = 1.4426950408889634f;
#pragma unroll 1
  for (int nt = nt0; nt <= nt1; ++nt) {
    int kv0 = nt * 64;
    bf16x8 kf[8];
#pragma unroll
    for (int f = 0; f < 8; f++)
      kf[f] = *(const bf16x8*)(Kp + (size_t)(kv0 + (f >> 2) * 32) * DHEAD + (f & 3) * 16);
    // S^T = K * Q^T
    f32x16 sacc[2] = {};
    __builtin_amdgcn_s_setprio(1);
#pragma unroll
    for (int kt = 0; kt < 4; kt++) {
      sacc[0] = MFMA32(kf[kt], qf[kt], sacc[0]);
      sacc[1] = MFMA32(kf[4 + kt], qf[kt], sacc[1]);
    }
    __builtin_amdgcn_s_setprio(0);
    // V frags (issued now; consumed after softmax — latency hidden)
    bf16x8 vf[8];
#pragma unroll
    for (int f = 0; f < 8; f++)
      vf[f] = *(const bf16x8*)(Vp + (size_t)((f >> 2) * 32) * S_LEN + kv0 + (f & 3) * 16);
    if (nt == ntd) {  // causal mask on the diagonal tile
#pragma unroll
      for (int r = 0; r < 16; r++) {
        int kvb = kv0 + (r & 3) + 8 * (r >> 2) + 4 * h;
        if (kvb > qrow) sacc[0][r] = -1e30f;
        if (kvb + 32 > qrow) sacc[1][r] = -1e30f;
      }
    }
    // row max: in-register tree + cross-half shfl
    float t8[8];
#pragma unroll
    for (int r = 0; r < 8; r++)
      t8[r] = fmaxf(fmaxf(sacc[0][r], sacc[0][r + 8]), fmaxf(sacc[1][r], sacc[1][r + 8]));
    float t4a = fmaxf(t8[0], t8[4]), t4b = fmaxf(t8[1], t8[5]);
    float t4c = fmaxf(t8[2], t8[6]), t4d = fmaxf(t8[3], t8[7]);
    float mx = fmaxf(fmaxf(t4a, t4b), fmaxf(t4c, t4d));
    mx = fmaxf(mx, __shfl_xor(mx, 32));
    bool up = mx > mrun + 5.5451774444795624f;  // defer-max, THR=8*ln2
    if (__any(up)) {
      float newm = up ? mx : mrun;
      float scl = fexp2((mrun - newm) * L2E);
      mrun = newm;
      lrun *= scl;
#pragma unroll
      for (int r = 0; r < 16; r++) { oacc[0][r] *= scl; oacc[1][r] *= scl; }
    }
    float nm2 = -mrun * L2E;
#pragma unroll
    for (int r = 0; r < 16; r++) {
      sacc[0][r] = fexp2(__builtin_fmaf(sacc[0][r], L2E, nm2));
      sacc[1][r] = fexp2(__builtin_fmaf(sacc[1][r], L2E, nm2));
    }
    float u8[8];
#pragma unroll
    for (int r = 0; r < 8; r++)
      u8[r] = (sacc[0][r] + sacc[0][r + 8]) + (sacc[1][r] + sacc[1][r + 8]);
    lrun += ((u8[0] + u8[4]) + (u8[1] + u8[5])) + ((u8[2] + u8[6]) + (u8[3] + u8[7]));
    // P^T -> bf16 B-frags
    u32x4 pa[4];
#pragma unroll
    for (int tau = 0; tau < 2; tau++) {
      u32x2 rA = plswap2(cvtpk(sacc[tau][0], sacc[tau][1]), cvtpk(sacc[tau][4], sacc[tau][5]));
      pa[2 * tau][0] = rA[0]; pa[2 * tau][2] = rA[1];
      u32x2 rC = plswap2(cvtpk(sacc[tau][2], sacc[tau][3]), cvtpk(sacc[tau][6], sacc[tau][7]));
      pa[2 * tau][1] = rC[0]; pa[2 * tau][3] = rC[1];
      u32x2 rA1 = plswap2(cvtpk(sacc[tau][8], sacc[tau][9]), cvtpk(sacc[tau][12], sacc[tau][13]));
      pa[2 * tau + 1][0] = rA1[0]; pa[2 * tau + 1][2] = rA1[1];
      u32x2 rC1 = plswap2(cvtpk(sacc[tau][10], sacc[tau][11]), cvtpk(sacc[tau][14], sacc[tau][15]));
      pa[2 * tau + 1][1] = rC1[0]; pa[2 * tau + 1][3] = rC1[1];
    }
    // O^T += V^T * P^T
    __builtin_amdgcn_s_setprio(1);
#pragma unroll
    for (int kt = 0; kt < 4; kt++) {
      bf16x8 pb = __builtin_bit_cast(bf16x8, pa[kt]);
      oacc[0] = MFMA32(vf[kt], pb, oacc[0]);
      oacc[1] = MFMA32(vf[4 + kt], pb, oacc[1]);
    }
    __builtin_amdgcn_s_setprio(0);
  }
  float lsum = lrun + __shfl_xor(lrun, 32);
  if (!partial) {
    float inv = 1.0f / lsum;
    int b = bh >> 4, hd = bh & 15;
    u16* Orow = O + ((size_t)(b * S_LEN + qrow)) * DMODEL + hd * 64;
#pragma unroll
    for (int dt = 0; dt < 2; dt++)
#pragma unroll
      for (int rr = 0; rr < 4; rr++) {
        uint2 pk;
        pk.x = cvtpk(oacc[dt][4 * rr + 0] * inv, oacc[dt][4 * rr + 1] * inv);
        pk.y = cvtpk(oacc[dt][4 * rr + 2] * inv, oacc[dt][4 * rr + 3] * inv);
        *(uint2*)(Orow + 32 * dt + 8 * rr + 4 * h) = pk;
      }
  } else {
    // slot offset: qt in [16,32): 2(qt-16); [32,48): 32+3(qt-32); [48,64): 80+4(qt-48)
    int off = (qt < 32) ? 2 * (qt - 16) : ((qt < 48) ? 32 + 3 * (qt - 32) : 80 + 4 * (qt - 48));
    int pi = bh * 144 + off + c;
    char* p = PB + (size_t)pi * 4352;
    u32x4 wv[4];
#pragma unroll
    for (int dt = 0; dt < 2; dt++)
#pragma unroll
      for (int rr = 0; rr < 4; rr++) {
        int wi = dt * 8 + rr * 2;
        ((u32*)wv)[wi] = cvtpk(oacc[dt][4 * rr + 0], oacc[dt][4 * rr + 1]);
        ((u32*)wv)[wi + 1] = cvtpk(oacc[dt][4 * rr + 2], oacc[dt][4 * rr + 3]);
      }
#pragma unroll
    for (int i = 0; i < 4; i++) *(u32x4*)(p + lane * 64 + i * 16) = wv[i];
    if (lane < 32) {
      float2 ml;
      ml.x = mrun;   // identical across halves (combined max)
      ml.y = lsum;   // combined sum
      *(float2*)(p + 4096 + ql * 8) = ml;
    }
  }
}

// ---------------- merge split-K partials (qt >= 16), C in 2..4 --------------
// Online running-max merge: no runtime-indexed register arrays (rule #20).
__global__ __launch_bounds__(256) void merge_k(const char* __restrict__ PB,
                                               u16* __restrict__ O) {
  int bh = blockIdx.x;
  int w = threadIdx.x >> 6, lane = threadIdx.x & 63;
  int ql = lane & 31, h = lane >> 5;
  int qt = 16 + blockIdx.y * 4 + w;  // grid.y = 12 -> qt 16..63
  int C = 1 + (qt >> 4);
  int off = (qt < 32) ? 2 * (qt - 16) : ((qt < 48) ? 32 + 3 * (qt - 32) : 80 + 4 * (qt - 48));
  const char* p = PB + (size_t)(bh * 144 + off) * 4352;
  const float L2E = 1.4426950408889634f;
  float m = -1e30f, l = 0.0f;
  float o[32];
#pragma unroll
  for (int i = 0; i < 32; i++) o[i] = 0.0f;
#pragma unroll 1
  for (int cc = 0; cc < C; ++cc, p += 4352) {
    float2 mlc = *(const float2*)(p + 4096 + ql * 8);
    float newm = fmaxf(m, mlc.x);
    float s_old = fexp2((m - newm) * L2E);
    float s_new = fexp2((mlc.x - newm) * L2E);
    m = newm;
    l = l * s_old + mlc.y * s_new;
#pragma unroll
    for (int i = 0; i < 16; i++) {
      u32 x = *(const u32*)(p + lane * 64 + i * 4);
      o[2 * i] = o[2 * i] * s_old + bf2f((u16)x) * s_new;
      o[2 * i + 1] = o[2 * i + 1] * s_old + bf2f((u16)(x >> 16)) * s_new;
    }
  }
  float inv = 1.0f / l;
  int qrow = qt * 32 + ql;
  int b = bh >> 4, hd = bh & 15;
  u16* Orow = O + ((size_t)(b * S_LEN + qrow)) * DMODEL + hd * 64;
#pragma unroll
  for (int dt = 0; dt < 2; dt++)
#pragma unroll
    for (int rr = 0; rr < 4; rr++) {
      int i0 = 2 * (dt * 8 + rr * 2);
      uint2 pk;
      pk.x = cvtpk(o[i0] * inv, o[i0 + 1] * inv);
      pk.y = cvtpk(o[i0 + 2] * inv, o[i0 + 3] * inv);
      *(uint2*)(Orow + 32 * dt + 8 * rr + 4 * h) = pk;
    }
}

// ---------------- launch -----------------------------------------------------
extern "C" void kernel_launch(void* const* d_in, const int* in_sizes, int n_in,
                              void* d_out, int out_size, void* d_ws, size_t ws_size,
                              hipStream_t stream) {
  (void)in_sizes; (void)n_in; (void)out_size; (void)ws_size;
  const float* x = (const float*)d_in[0];
  const int* tpos = (const int*)d_in[1];
  const float* Wq = (const float*)d_in[2];
  const float* Wk = (const float*)d_in[3];
  const float* Wv = (const float*)d_in[4];
  const float* Wo = (const float*)d_in[5];
  char* ws = (char*)d_ws;
  // workspace map (56 MB). PB (attn partials, 19.2 MB) overlays xb/wq/wk/wv
  // which are dead after gemm<1>. wob stays live until gemm<0>.
  u16* xb  = (u16*)(ws + ((size_t)0 << 20));   // 8 MB  (dead after gemm<1>)
  u16* wqb = (u16*)(ws + ((size_t)8 << 20));   // 2 MB  (dead after gemm<1>)
  u16* wkb = (u16*)(ws + ((size_t)10 << 20));  // 2 MB  (dead after gemm<1>)
  u16* wvb = (u16*)(ws + ((size_t)12 << 20));  // 2 MB  (dead after gemm<1>)
  char* PB = ws;                               // 22 MB partial region [0,22)
  u16* wob = (u16*)(ws + ((size_t)22 << 20));  // 2 MB
  u16* Qb  = (u16*)(ws + ((size_t)24 << 20));  // 8 MB  [B,H,S,DK]
  u16* Kb  = (u16*)(ws + ((size_t)32 << 20));  // 8 MB
  u16* VTb = (u16*)(ws + ((size_t)40 << 20));  // 8 MB  [B,H,DK,S] (direct from gemm)
  u16* Ob  = (u16*)(ws + ((size_t)48 << 20));  // 8 MB  [B,S,DMODEL] bf16

  convert_k<<<dim3(1024, 8), 256, 0, stream>>>(x, Wq, Wk, Wv, Wo, xb, wqb, wkb, wvb, wob);
  gemm128<1><<<dim3(32, 8, 3), 256, 0, stream>>>(xb, wqb, wkb, wvb,
                                                 (void*)Qb, (void*)Kb, (void*)VTb);
  rope_k<<<dim3(1024, 2), 256, 0, stream>>>(Qb, Kb, tpos);
  attn_k<<<dim3(32, 160), 64, 0, stream>>>(Qb, Kb, VTb, Ob, PB);
  merge_k<<<dim3(32, 12), 256, 0, stream>>>(PB, Ob);
  gemm128<0><<<dim3(32, 8, 1), 256, 0, stream>>>(Ob, wob, wob, wob, d_out, d_out, d_out);
}

// Round 9
// 136.355 us; speedup vs baseline: 1.2751x; 1.2751x over previous
//
#include <hip/hip_runtime.h>
#include <stdint.h>

#define S_LEN 2048
#define NHEADS 16
#define DHEAD 64
#define DMODEL 1024

typedef unsigned short u16;
typedef unsigned int u32;
typedef __bf16 bf16x8 __attribute__((ext_vector_type(8)));
typedef float f32x4 __attribute__((ext_vector_type(4)));
typedef float f32x16 __attribute__((ext_vector_type(16)));
typedef u32 u32x4 __attribute__((ext_vector_type(4)));
typedef u32 u32x2 __attribute__((ext_vector_type(2)));

__device__ __forceinline__ float bf2f(u16 u) {
  u32 x = ((u32)u) << 16;
  float f;
  __builtin_memcpy(&f, &x, 4);
  return f;
}
__device__ __forceinline__ u16 f2bf(float f) {
  u32 x;
  __builtin_memcpy(&x, &f, 4);
  x += 0x7FFFu + ((x >> 16) & 1u);
  return (u16)(x >> 16);
}
// packed f32 pair -> bf16 pair (lo = a, hi = b)
__device__ __forceinline__ u32 cvtpk(float a, float b) {
  u32 r;
  asm("v_cvt_pk_bf16_f32 %0, %1, %2" : "=v"(r) : "v"(a), "v"(b));
  return r;
}
// r[0] = {a_lo, b_lo}, r[1] = {a_hi, b_hi}
__device__ __forceinline__ u32x2 plswap2(u32 a, u32 b) {
  return __builtin_amdgcn_permlane32_swap(a, b, false, false);
}
// single-instruction exp2
__device__ __forceinline__ float fexp2(float x) {
  float r;
  asm("v_exp_f32 %0, %1" : "=v"(r) : "v"(x));
  return r;
}

#define AS1 __attribute__((address_space(1)))
#define AS3 __attribute__((address_space(3)))
__device__ __forceinline__ void gload16(const void* g, void* l) {
  __builtin_amdgcn_global_load_lds((AS1 void*)g, (AS3 void*)l, 16, 0, 0);
}

#define MFMA32(a, b, c) __builtin_amdgcn_mfma_f32_32x32x16_bf16(a, b, c, 0, 0, 0)

// ---------------- f32 -> bf16 convert: x (4 parts of 1M) + 4 weight mats ----
__global__ __launch_bounds__(256) void convert_k(
    const float* __restrict__ x, const float* __restrict__ wq, const float* __restrict__ wk,
    const float* __restrict__ wv, const float* __restrict__ wo,
    u16* __restrict__ xb, u16* __restrict__ wqb, u16* __restrict__ wkb,
    u16* __restrict__ wvb, u16* __restrict__ wob) {
  int part = blockIdx.y;
  const float* src;
  u16* dst;
  size_t base = 0;
  if (part < 4) { src = x; dst = xb; base = (size_t)part << 20; }
  else if (part == 4) { src = wq; dst = wqb; }
  else if (part == 5) { src = wk; dst = wkb; }
  else if (part == 6) { src = wv; dst = wvb; }
  else { src = wo; dst = wob; }
  size_t i = base + ((size_t)(blockIdx.x * 256 + threadIdx.x)) * 4;
  float4 v = *(const float4*)(src + i);
  ushort4 o;
  o.x = f2bf(v.x); o.y = f2bf(v.y); o.z = f2bf(v.z); o.w = f2bf(v.w);
  *(ushort4*)(dst + i) = o;
}

// ---------------- 128x128 bf16 GEMM, C = A * B^T (A:[M][K], B:[N][K]) ------
// MODE 0: write f32 row-major [M][N].
// MODE 1: z<2 -> bf16 [B,H,S,DK]; z==2 -> bf16 V^T [B,H,DK,S].
template <int MODE>
__global__ __launch_bounds__(256) void gemm128(
    const u16* __restrict__ A, const u16* __restrict__ B0, const u16* __restrict__ B1,
    const u16* __restrict__ B2, void* __restrict__ O0, void* __restrict__ O1,
    void* __restrict__ O2) {
  __shared__ alignas(16) u16 As[128 * 64];
  __shared__ alignas(16) u16 Bs[128 * 64];
  int z = blockIdx.z;
  const u16* Bm = (z == 0) ? B0 : ((z == 1) ? B1 : B2);
  void* Om = (z == 0) ? O0 : ((z == 1) ? O1 : O2);
  int m0 = blockIdx.x * 128, n0 = blockIdx.y * 128;
  int t = threadIdx.x;
  int w = t >> 6, lane = t & 63, lr = lane >> 4, lc = lane & 15;
  int wr = w >> 1, wc = w & 1;
  f32x4 acc[4][4] = {};
  int srow = t >> 3;
  int scolb = (t & 7) * 16;
  const char* Ag = (const char*)A;
  const char* Bg = (const char*)Bm;
  for (int k0 = 0; k0 < DMODEL; k0 += 64) {
#pragma unroll
    for (int i = 0; i < 4; i++) {
      gload16(Ag + ((size_t)(m0 + srow + i * 32) * DMODEL + k0) * 2 + scolb,
              (char*)As + i * 4096 + w * 1024);
      gload16(Bg + ((size_t)(n0 + srow + i * 32) * DMODEL + k0) * 2 + scolb,
              (char*)Bs + i * 4096 + w * 1024);
    }
    __syncthreads();
#pragma unroll
    for (int kk = 0; kk < 2; kk++) {
      bf16x8 af[4], bfr[4];
#pragma unroll
      for (int mi = 0; mi < 4; mi++)
        af[mi] = *(const bf16x8*)(As + (wr * 64 + mi * 16 + lc) * 64 + kk * 32 + lr * 8);
#pragma unroll
      for (int ni = 0; ni < 4; ni++)
        bfr[ni] = *(const bf16x8*)(Bs + (wc * 64 + ni * 16 + lc) * 64 + kk * 32 + lr * 8);
#pragma unroll
      for (int mi = 0; mi < 4; mi++)
#pragma unroll
        for (int ni = 0; ni < 4; ni++)
          acc[mi][ni] =
              __builtin_amdgcn_mfma_f32_16x16x32_bf16(af[mi], bfr[ni], acc[mi][ni], 0, 0, 0);
    }
    __syncthreads();
  }
  if constexpr (MODE == 0) {
    float* Of = (float*)Om;
#pragma unroll
    for (int mi = 0; mi < 4; mi++)
#pragma unroll
      for (int ni = 0; ni < 4; ni++) {
        int m = m0 + wr * 64 + mi * 16 + lr * 4;
        int n = n0 + wc * 64 + ni * 16 + lc;
#pragma unroll
        for (int r = 0; r < 4; r++) Of[(size_t)(m + r) * DMODEL + n] = acc[mi][ni][r];
      }
  } else {
    __shared__ alignas(16) u16 Epi[4][2560];  // per-wave 5120B scratch
    u16* Ew = Epi[w];
    int b = m0 >> 11;
    if (z != 2) {
      u16* Oh = (u16*)Om;
      int h = (n0 >> 6) + wc;
      int rr = lane >> 2, qq = lane & 3;
#pragma unroll
      for (int mi = 0; mi < 4; mi++) {
#pragma unroll
        for (int ni = 0; ni < 4; ni++)
#pragma unroll
          for (int r = 0; r < 4; r++)
            Ew[(lr * 4 + r) * 72 + ni * 16 + lc] = f2bf(acc[mi][ni][r]);
        asm volatile("s_waitcnt lgkmcnt(0)" ::: "memory");
        __builtin_amdgcn_sched_barrier(0);
        int s = (m0 + wr * 64 + mi * 16 + rr) & 2047;
        u16* dst = Oh + ((size_t)((b * NHEADS + h) * S_LEN + s)) * DHEAD + qq * 16;
        u32x4 c0 = *(const u32x4*)(Ew + rr * 72 + qq * 16);
        u32x4 c1 = *(const u32x4*)(Ew + rr * 72 + qq * 16 + 8);
        *(u32x4*)dst = c0;
        *(u32x4*)(dst + 8) = c1;
        __builtin_amdgcn_sched_barrier(0);
      }
    } else {
      u16* VTo = (u16*)Om;
      int bh = b * NHEADS + (n0 >> 6) + wc;
      int scol = (m0 & 2047) + wr * 64;
#pragma unroll
      for (int mi = 0; mi < 4; mi++) {
#pragma unroll
        for (int ni = 0; ni < 4; ni++) {
          int nloc = ni * 16 + lc;
#pragma unroll
          for (int k = 0; k < 2; k++) {
            u32 p = cvtpk(acc[mi][ni][2 * k], acc[mi][ni][2 * k + 1]);
            *(u32*)(Ew + nloc * 40 + lr * 4 + 2 * k) = p;
          }
        }
        asm volatile("s_waitcnt lgkmcnt(0)" ::: "memory");
        __builtin_amdgcn_sched_barrier(0);
        u32x4 c0 = *(const u32x4*)(Ew + lane * 40);
        u32x4 c1 = *(const u32x4*)(Ew + lane * 40 + 8);
        u16* dst = VTo + ((size_t)(bh * DHEAD + lane)) * S_LEN + scol + mi * 16;
        *(u32x4*)dst = c0;
        *(u32x4*)(dst + 8) = c1;
        __builtin_amdgcn_sched_barrier(0);
      }
    }
  }
}

// ---------------- RoPE in-place on bf16 Q (y=0, with 1/8 scale) and K (y=1) -
__global__ __launch_bounds__(256) void rope_k(u16* __restrict__ Q, u16* __restrict__ K,
                                              const int* __restrict__ pos) {
  int sel = blockIdx.y;
  u16* Aq = sel ? K : Q;
  float oscale = sel ? 1.0f : 0.125f;
  int idx = blockIdx.x * 256 + threadIdx.x;
  int r = idx >> 2, seg = idx & 3;
  int b = r >> 15, s = r & 2047;
  float p = (float)pos[(b << 11) + s];
  u16* ptr = Aq + (size_t)r * DHEAD + seg * 16;
  alignas(16) u16 e[16];
  *(uint4*)&e[0] = *(const uint4*)ptr;
  *(uint4*)&e[8] = *(const uint4*)(ptr + 8);
#pragma unroll
  for (int j = 0; j < 8; j++) {
    int i = seg * 8 + j;
    float fr = exp2f(-0.4152410118407687f * (float)i);
    float ang = p * fr;
    float sn, cs;
    __sincosf(ang, &sn, &cs);
    float ev = bf2f(e[2 * j]), ov = bf2f(e[2 * j + 1]);
    e[2 * j] = f2bf((ev * cs - ov * sn) * oscale);
    e[2 * j + 1] = f2bf((ev * sn + ov * cs) * oscale);
  }
  *(uint4*)ptr = *(const uint4*)&e[0];
  *(uint4*)(ptr + 8) = *(const uint4*)&e[8];
}

// ---------------- causal flash attention, v9 = R4 base + KVBLK=128 ---------
// 4 waves x 32 q-rows = 128 q/block; stage 128 kv (K[128][64] + VT[64][128],
// XOR-swizzled, coalesced global_load_lds) per vmcnt+barrier; 2 inner 64-kv
// tiles per stage -> half the barriers/drains of R4. In-register softmax
// (swapped QK^T), defer-max, cvt_pk+permlane P-pack. Grid 32 x 16, heavy qc
// first; bh fastest (XCD L2 locality).
struct AttnSt {
  f32x16 oacc[2];
  float mrun, lrun;
};

__device__ __forceinline__ void attn_tile64(
    const char* kbuf, const char* vbuf, int tb, int kv0, bool domask,
    const bf16x8 (&qf)[4], int qrow, int h, int ql, AttnSt& st) {
  const float L2E = 1.4426950408889634f;
  int swz = ql & 7;
  // S^T = K * Q^T
  f32x16 sacc[2] = {};
  __builtin_amdgcn_s_setprio(1);
#pragma unroll
  for (int kt = 0; kt < 4; kt++) {
    int c = ((2 * kt + h) ^ swz) << 4;
    const char* kr = kbuf + (size_t)tb * 8192;
    bf16x8 k0 = *(const bf16x8*)(kr + ql * 128 + c);
    bf16x8 k1 = *(const bf16x8*)(kr + (32 + ql) * 128 + c);
    sacc[0] = MFMA32(k0, qf[kt], sacc[0]);
    sacc[1] = MFMA32(k1, qf[kt], sacc[1]);
  }
  __builtin_amdgcn_s_setprio(0);
  if (domask) {
#pragma unroll
    for (int r = 0; r < 16; r++) {
      int kvb = kv0 + (r & 3) + 8 * (r >> 2) + 4 * h;
      if (kvb > qrow) sacc[0][r] = -1e30f;
      if (kvb + 32 > qrow) sacc[1][r] = -1e30f;
    }
  }
  // row max: in-register tree + cross-half shfl
  float t8[8];
#pragma unroll
  for (int r = 0; r < 8; r++)
    t8[r] = fmaxf(fmaxf(sacc[0][r], sacc[0][r + 8]), fmaxf(sacc[1][r], sacc[1][r + 8]));
  float t4a = fmaxf(t8[0], t8[4]), t4b = fmaxf(t8[1], t8[5]);
  float t4c = fmaxf(t8[2], t8[6]), t4d = fmaxf(t8[3], t8[7]);
  float mx = fmaxf(fmaxf(t4a, t4b), fmaxf(t4c, t4d));
  mx = fmaxf(mx, __shfl_xor(mx, 32));
  bool up = mx > st.mrun + 5.5451774444795624f;  // defer-max, THR=8*ln2
  if (__any(up)) {
    float newm = up ? mx : st.mrun;
    float scl = fexp2((st.mrun - newm) * L2E);
    st.mrun = newm;
    st.lrun *= scl;
#pragma unroll
    for (int r = 0; r < 16; r++) { st.oacc[0][r] *= scl; st.oacc[1][r] *= scl; }
  }
  float nm2 = -st.mrun * L2E;
#pragma unroll
  for (int r = 0; r < 16; r++) {
    sacc[0][r] = fexp2(__builtin_fmaf(sacc[0][r], L2E, nm2));
    sacc[1][r] = fexp2(__builtin_fmaf(sacc[1][r], L2E, nm2));
  }
  float u8[8];
#pragma unroll
  for (int r = 0; r < 8; r++)
    u8[r] = (sacc[0][r] + sacc[0][r + 8]) + (sacc[1][r] + sacc[1][r + 8]);
  st.lrun += ((u8[0] + u8[4]) + (u8[1] + u8[5])) + ((u8[2] + u8[6]) + (u8[3] + u8[7]));
  // P^T -> bf16 B-frags
  u32x4 pa[4];
#pragma unroll
  for (int tau = 0; tau < 2; tau++) {
    u32x2 rA = plswap2(cvtpk(sacc[tau][0], sacc[tau][1]), cvtpk(sacc[tau][4], sacc[tau][5]));
    pa[2 * tau][0] = rA[0]; pa[2 * tau][2] = rA[1];
    u32x2 rC = plswap2(cvtpk(sacc[tau][2], sacc[tau][3]), cvtpk(sacc[tau][6], sacc[tau][7]));
    pa[2 * tau][1] = rC[0]; pa[2 * tau][3] = rC[1];
    u32x2 rA1 = plswap2(cvtpk(sacc[tau][8], sacc[tau][9]), cvtpk(sacc[tau][12], sacc[tau][13]));
    pa[2 * tau + 1][0] = rA1[0]; pa[2 * tau + 1][2] = rA1[1];
    u32x2 rC1 = plswap2(cvtpk(sacc[tau][10], sacc[tau][11]), cvtpk(sacc[tau][14], sacc[tau][15]));
    pa[2 * tau + 1][1] = rC1[0]; pa[2 * tau + 1][3] = rC1[1];
  }
  // O^T += V^T * P^T
  __builtin_amdgcn_s_setprio(1);
#pragma unroll
  for (int kt = 0; kt < 4; kt++) {
    int c = (tb * 8 + ((2 * kt + h) ^ swz)) << 4;
    bf16x8 v0 = *(const bf16x8*)(vbuf + ql * 256 + c);
    bf16x8 v1 = *(const bf16x8*)(vbuf + (32 + ql) * 256 + c);
    bf16x8 pb = __builtin_bit_cast(bf16x8, pa[kt]);
    st.oacc[0] = MFMA32(v0, pb, st.oacc[0]);
    st.oacc[1] = MFMA32(v1, pb, st.oacc[1]);
  }
  __builtin_amdgcn_s_setprio(0);
}

__global__ __launch_bounds__(256) void attn_k(const u16* __restrict__ Q,
                                              const u16* __restrict__ K,
                                              const u16* __restrict__ VT,
                                              u16* __restrict__ O) {
  __shared__ alignas(16) u16 Ks[2][128 * 64];  // [kv][d], swizzled, 16KB each
  __shared__ alignas(16) u16 Vs[2][64 * 128];  // [d][kv], swizzled, 16KB each
  int bh = blockIdx.x;            // fast dim -> bh%8 tracks XCD
  int qc = 15 - (int)blockIdx.y;  // heavy blocks first
  int t = threadIdx.x, w = t >> 6, lane = t & 63;
  int ql = lane & 31, h = lane >> 5;
  size_t base = (size_t)bh * (S_LEN * DHEAD);
  int qrow = qc * 128 + w * 32 + ql;
  bf16x8 qf[4];
#pragma unroll
  for (int kt = 0; kt < 4; kt++)
    qf[kt] = *(const bf16x8*)(Q + base + (size_t)qrow * DHEAD + kt * 16 + h * 8);
  AttnSt st;
  st.oacc[0] = f32x16{};
  st.oacc[1] = f32x16{};
  st.mrun = -1e30f;
  st.lrun = 0.0f;
  // staging source pointers (pre-swizzled global chunks; LDS dest is linear)
  int krow = t >> 3;
  int kc = ((t & 7) ^ (krow & 7)) << 3;  // u16 units
  const u16* Kg0 = K + base + (size_t)krow * DHEAD + kc;
  int vrow = t >> 4;
  int vc = ((t & 15) ^ (vrow & 7)) << 3;  // u16 units
  const u16* Vg0 = VT + (size_t)bh * DHEAD * S_LEN + (size_t)vrow * S_LEN + vc;
  char* klb = (char*)&Ks[0][0] + w * 1024;
  char* vlb = (char*)&Vs[0][0] + w * 1024;

#define STAGE(s, buf)                                                    \
  do {                                                                   \
    int kv0s = (s) * 128;                                                \
    char* kl = klb + (buf) * 16384;                                      \
    char* vl = vlb + (buf) * 16384;                                      \
    _Pragma("unroll")                                                    \
    for (int p = 0; p < 4; p++)                                          \
      gload16(Kg0 + (size_t)(kv0s + p * 32) * DHEAD, kl + p * 4096);     \
    _Pragma("unroll")                                                    \
    for (int p = 0; p < 4; p++)                                          \
      gload16(Vg0 + (size_t)(p * 16) * S_LEN + kv0s, vl + p * 4096);     \
  } while (0)

  STAGE(0, 0);
  asm volatile("s_waitcnt vmcnt(0)" ::: "memory");
  __builtin_amdgcn_s_barrier();
  asm volatile("" ::: "memory");
  int cur = 0;
#pragma unroll 1
  for (int s = 0; s <= qc; ++s) {
    if (s < qc) STAGE(s + 1, cur ^ 1);  // loads in flight across this stage
    const char* kb = (const char*)&Ks[cur][0];
    const char* vb = (const char*)&Vs[cur][0];
    bool diag = (s == qc);
    // tile a: kv [128s, 128s+64)
    attn_tile64(kb, vb, 0, s * 128, diag && (w < 2), qf, qrow, h, ql, st);
    // tile b: kv [128s+64, 128s+128); on diagonal stage waves 0,1 skip it
    if (!(diag && w < 2))
      attn_tile64(kb, vb, 1, s * 128 + 64, diag, qf, qrow, h, ql, st);
    asm volatile("s_waitcnt vmcnt(0)" ::: "memory");
    __builtin_amdgcn_s_barrier();
    asm volatile("" ::: "memory");
    cur ^= 1;
  }
#undef STAGE
  // combine cross-half row-sum, normalize, packed stores
  float lsum = st.lrun + __shfl_xor(st.lrun, 32);
  float inv = 1.0f / lsum;
  int b = bh >> 4, hd = bh & 15;
  u16* Orow = O + ((size_t)(b * S_LEN + qrow)) * DMODEL + hd * 64;
#pragma unroll
  for (int dt = 0; dt < 2; dt++)
#pragma unroll
    for (int rr = 0; rr < 4; rr++) {
      uint2 pk;
      pk.x = cvtpk(st.oacc[dt][4 * rr + 0] * inv, st.oacc[dt][4 * rr + 1] * inv);
      pk.y = cvtpk(st.oacc[dt][4 * rr + 2] * inv, st.oacc[dt][4 * rr + 3] * inv);
      *(uint2*)(Orow + 32 * dt + 8 * rr + 4 * h) = pk;
    }
}

// ---------------- launch -----------------------------------------------------
extern "C" void kernel_launch(void* const* d_in, const int* in_sizes, int n_in,
                              void* d_out, int out_size, void* d_ws, size_t ws_size,
                              hipStream_t stream) {
  (void)in_sizes; (void)n_in; (void)out_size; (void)ws_size;
  const float* x = (const float*)d_in[0];
  const int* tpos = (const int*)d_in[1];
  const float* Wq = (const float*)d_in[2];
  const float* Wk = (const float*)d_in[3];
  const float* Wv = (const float*)d_in[4];
  const float* Wo = (const float*)d_in[5];
  char* ws = (char*)d_ws;
  // workspace map (48 MB used of 56)
  u16* xb  = (u16*)(ws + ((size_t)0 << 20));   // 8 MB  [4096][1024] bf16
  u16* wqb = (u16*)(ws + ((size_t)8 << 20));   // 2 MB
  u16* wkb = (u16*)(ws + ((size_t)10 << 20));  // 2 MB
  u16* wvb = (u16*)(ws + ((size_t)12 << 20));  // 2 MB
  u16* wob = (u16*)(ws + ((size_t)14 << 20));  // 2 MB
  u16* Qb  = (u16*)(ws + ((size_t)16 << 20));  // 8 MB  [B,H,S,DK]
  u16* Kb  = (u16*)(ws + ((size_t)24 << 20));  // 8 MB  [B,H,S,DK]
  u16* VTb = (u16*)(ws + ((size_t)32 << 20));  // 8 MB  [B,H,DK,S] (direct from gemm)
  u16* Ob  = (u16*)(ws + ((size_t)40 << 20));  // 8 MB  [B,S,DMODEL] bf16

  convert_k<<<dim3(1024, 8), 256, 0, stream>>>(x, Wq, Wk, Wv, Wo, xb, wqb, wkb, wvb, wob);
  gemm128<1><<<dim3(32, 8, 3), 256, 0, stream>>>(xb, wqb, wkb, wvb,
                                                 (void*)Qb, (void*)Kb, (void*)VTb);
  rope_k<<<dim3(1024, 2), 256, 0, stream>>>(Qb, Kb, tpos);
  attn_k<<<dim3(32, 16), 256, 0, stream>>>(Qb, Kb, VTb, Ob);
  gemm128<0><<<dim3(32, 8, 1), 256, 0, stream>>>(Ob, wob, wob, wob, d_out, d_out, d_out);
}

// Round 10
// 133.788 us; speedup vs baseline: 1.2995x; 1.0192x over previous
//
#include <hip/hip_runtime.h>
#include <stdint.h>

#define S_LEN 2048
#define NHEADS 16
#define DHEAD 64
#define DMODEL 1024

typedef unsigned short u16;
typedef unsigned int u32;
typedef __bf16 bf16x8 __attribute__((ext_vector_type(8)));
typedef float f32x4 __attribute__((ext_vector_type(4)));
typedef float f32x16 __attribute__((ext_vector_type(16)));
typedef u32 u32x4 __attribute__((ext_vector_type(4)));
typedef u32 u32x2 __attribute__((ext_vector_type(2)));

__device__ __forceinline__ float bf2f(u16 u) {
  u32 x = ((u32)u) << 16;
  float f;
  __builtin_memcpy(&f, &x, 4);
  return f;
}
__device__ __forceinline__ u16 f2bf(float f) {
  u32 x;
  __builtin_memcpy(&x, &f, 4);
  x += 0x7FFFu + ((x >> 16) & 1u);
  return (u16)(x >> 16);
}
// packed f32 pair -> bf16 pair (lo = a, hi = b)
__device__ __forceinline__ u32 cvtpk(float a, float b) {
  u32 r;
  asm("v_cvt_pk_bf16_f32 %0, %1, %2" : "=v"(r) : "v"(a), "v"(b));
  return r;
}
// r[0] = {a_lo, b_lo}, r[1] = {a_hi, b_hi}
__device__ __forceinline__ u32x2 plswap2(u32 a, u32 b) {
  return __builtin_amdgcn_permlane32_swap(a, b, false, false);
}
// single-instruction exp2
__device__ __forceinline__ float fexp2(float x) {
  float r;
  asm("v_exp_f32 %0, %1" : "=v"(r) : "v"(x));
  return r;
}

#define AS1 __attribute__((address_space(1)))
#define AS3 __attribute__((address_space(3)))
__device__ __forceinline__ void gload16(const void* g, void* l) {
  __builtin_amdgcn_global_load_lds((AS1 void*)g, (AS3 void*)l, 16, 0, 0);
}

#define MFMA16(a, b, c) __builtin_amdgcn_mfma_f32_16x16x32_bf16(a, b, c, 0, 0, 0)
#define MFMA32(a, b, c) __builtin_amdgcn_mfma_f32_32x32x16_bf16(a, b, c, 0, 0, 0)

// ---------------- f32 -> bf16 convert: x (4 parts of 1M) + 4 weight mats ----
__global__ __launch_bounds__(256) void convert_k(
    const float* __restrict__ x, const float* __restrict__ wq, const float* __restrict__ wk,
    const float* __restrict__ wv, const float* __restrict__ wo,
    u16* __restrict__ xb, u16* __restrict__ wqb, u16* __restrict__ wkb,
    u16* __restrict__ wvb, u16* __restrict__ wob) {
  int part = blockIdx.y;
  const float* src;
  u16* dst;
  size_t base = 0;
  if (part < 4) { src = x; dst = xb; base = (size_t)part << 20; }
  else if (part == 4) { src = wq; dst = wqb; }
  else if (part == 5) { src = wk; dst = wkb; }
  else if (part == 6) { src = wv; dst = wvb; }
  else { src = wo; dst = wob; }
  size_t i = base + ((size_t)(blockIdx.x * 256 + threadIdx.x)) * 4;
  float4 v = *(const float4*)(src + i);
  ushort4 o;
  o.x = f2bf(v.x); o.y = f2bf(v.y); o.z = f2bf(v.z); o.w = f2bf(v.w);
  *(ushort4*)(dst + i) = o;
}

// ---------------- 128x128 bf16 GEMM, C = A * B^T (A:[M][K], B:[N][K]) ------
// MODE 0: f32 row-major [M][N], swapped acc (lane holds 4 consecutive n) ->
//         float4 stores.
// MODE 1: bf16 [B,H,S,DK] with FUSED ROPE (z=0: Q with 1/8 scale, z=1: K);
//         swapped acc -> lane holds 2 rotation pairs -> 8B packed stores.
// MODE 2: bf16 V^T [B,H,DK,S]; normal acc (lane holds 4 consecutive s) ->
//         8B packed stores. No LDS epilogue anywhere (R9: 9.5e6 bank confl).
template <int MODE>
__global__ __launch_bounds__(256) void gemm128(
    const u16* __restrict__ A, const u16* __restrict__ B0, const u16* __restrict__ B1,
    void* __restrict__ O0, void* __restrict__ O1, const int* __restrict__ pos) {
  __shared__ alignas(16) u16 As[128 * 64];
  __shared__ alignas(16) u16 Bs[128 * 64];
  int z = blockIdx.z;
  const u16* Bm = (z == 0) ? B0 : B1;
  int m0 = blockIdx.x * 128, n0 = blockIdx.y * 128;
  int t = threadIdx.x;
  int w = t >> 6, lane = t & 63, lr = lane >> 4, lc = lane & 15;
  int wr = w >> 1, wc = w & 1;
  f32x4 acc[4][4] = {};
  int srow = t >> 3;
  int scolb = (t & 7) * 16;
  const char* Ag = (const char*)A;
  const char* Bg = (const char*)Bm;
  for (int k0 = 0; k0 < DMODEL; k0 += 64) {
#pragma unroll
    for (int i = 0; i < 4; i++) {
      gload16(Ag + ((size_t)(m0 + srow + i * 32) * DMODEL + k0) * 2 + scolb,
              (char*)As + i * 4096 + w * 1024);
      gload16(Bg + ((size_t)(n0 + srow + i * 32) * DMODEL + k0) * 2 + scolb,
              (char*)Bs + i * 4096 + w * 1024);
    }
    __syncthreads();
#pragma unroll
    for (int kk = 0; kk < 2; kk++) {
      bf16x8 af[4], bfr[4];
#pragma unroll
      for (int mi = 0; mi < 4; mi++)
        af[mi] = *(const bf16x8*)(As + (wr * 64 + mi * 16 + lc) * 64 + kk * 32 + lr * 8);
#pragma unroll
      for (int ni = 0; ni < 4; ni++)
        bfr[ni] = *(const bf16x8*)(Bs + (wc * 64 + ni * 16 + lc) * 64 + kk * 32 + lr * 8);
#pragma unroll
      for (int mi = 0; mi < 4; mi++)
#pragma unroll
        for (int ni = 0; ni < 4; ni++) {
          if constexpr (MODE == 2)
            acc[mi][ni] = MFMA16(af[mi], bfr[ni], acc[mi][ni]);  // C
          else
            acc[mi][ni] = MFMA16(bfr[ni], af[mi], acc[mi][ni]);  // C^T frag
        }
    }
    __syncthreads();
  }
  if constexpr (MODE == 0) {
    // swapped frag: m = ...+lc, n = ...+lr*4+r (4 consecutive)
    float* Of = (float*)O0;
#pragma unroll
    for (int mi = 0; mi < 4; mi++) {
      int m = m0 + wr * 64 + mi * 16 + lc;
#pragma unroll
      for (int ni = 0; ni < 4; ni++) {
        int n = n0 + wc * 64 + ni * 16 + lr * 4;
        *(f32x4*)(Of + (size_t)m * DMODEL + n) = acc[mi][ni];
      }
    }
  } else if constexpr (MODE == 1) {
    // swapped frag: s = ...+lc, d = ni*16+lr*4+{0..3} = 2 rope pairs
    u16* Oh = z ? (u16*)O1 : (u16*)O0;
    float oscale = z ? 1.0f : 0.125f;  // fold 1/sqrt(DK) into Q
    int h = (n0 >> 6) + wc;
    float fr0[4], fr1[4];
#pragma unroll
    for (int ni = 0; ni < 4; ni++) {
      int i0 = ni * 8 + lr * 2;  // pair index = d/2
      fr0[ni] = exp2f(-0.4152410118407687f * (float)i0);
      fr1[ni] = exp2f(-0.4152410118407687f * (float)(i0 + 1));
    }
#pragma unroll
    for (int mi = 0; mi < 4; mi++) {
      int sg = m0 + wr * 64 + mi * 16 + lc;
      float p = (float)pos[sg];
      int b = sg >> 11, s = sg & 2047;
      u16* dst = Oh + ((size_t)((b * NHEADS + h) * S_LEN + s)) * DHEAD;
#pragma unroll
      for (int ni = 0; ni < 4; ni++) {
        float sn0, cs0, sn1, cs1;
        __sincosf(p * fr0[ni], &sn0, &cs0);
        __sincosf(p * fr1[ni], &sn1, &cs1);
        f32x4 a = acc[mi][ni];
        uint2 pk;
        pk.x = cvtpk((a[0] * cs0 - a[1] * sn0) * oscale,
                     (a[0] * sn0 + a[1] * cs0) * oscale);
        pk.y = cvtpk((a[2] * cs1 - a[3] * sn1) * oscale,
                     (a[2] * sn1 + a[3] * cs1) * oscale);
        *(uint2*)(dst + ni * 16 + lr * 4) = pk;
      }
    }
  } else {
    // normal frag: d = ni*16+lc, s = ...+lr*4+{0..3} (4 consecutive)
    u16* VTo = (u16*)O0;
    int bh = (m0 >> 11) * NHEADS + (n0 >> 6) + wc;
    int scol = (m0 & 2047) + wr * 64;
#pragma unroll
    for (int mi = 0; mi < 4; mi++)
#pragma unroll
      for (int ni = 0; ni < 4; ni++) {
        int d = ni * 16 + lc;
        f32x4 a = acc[mi][ni];
        uint2 pk;
        pk.x = cvtpk(a[0], a[1]);
        pk.y = cvtpk(a[2], a[3]);
        *(uint2*)(VTo + ((size_t)bh * DHEAD + d) * S_LEN + scol + mi * 16 + lr * 4) = pk;
      }
  }
}

// ---------------- causal flash attention, v9 (unchanged from R9) ------------
struct AttnSt {
  f32x16 oacc[2];
  float mrun, lrun;
};

__device__ __forceinline__ void attn_tile64(
    const char* kbuf, const char* vbuf, int tb, int kv0, bool domask,
    const bf16x8 (&qf)[4], int qrow, int h, int ql, AttnSt& st) {
  const float L2E = 1.4426950408889634f;
  int swz = ql & 7;
  // S^T = K * Q^T
  f32x16 sacc[2] = {};
  __builtin_amdgcn_s_setprio(1);
#pragma unroll
  for (int kt = 0; kt < 4; kt++) {
    int c = ((2 * kt + h) ^ swz) << 4;
    const char* kr = kbuf + (size_t)tb * 8192;
    bf16x8 k0 = *(const bf16x8*)(kr + ql * 128 + c);
    bf16x8 k1 = *(const bf16x8*)(kr + (32 + ql) * 128 + c);
    sacc[0] = MFMA32(k0, qf[kt], sacc[0]);
    sacc[1] = MFMA32(k1, qf[kt], sacc[1]);
  }
  __builtin_amdgcn_s_setprio(0);
  if (domask) {
#pragma unroll
    for (int r = 0; r < 16; r++) {
      int kvb = kv0 + (r & 3) + 8 * (r >> 2) + 4 * h;
      if (kvb > qrow) sacc[0][r] = -1e30f;
      if (kvb + 32 > qrow) sacc[1][r] = -1e30f;
    }
  }
  // row max: in-register tree + cross-half shfl
  float t8[8];
#pragma unroll
  for (int r = 0; r < 8; r++)
    t8[r] = fmaxf(fmaxf(sacc[0][r], sacc[0][r + 8]), fmaxf(sacc[1][r], sacc[1][r + 8]));
  float t4a = fmaxf(t8[0], t8[4]), t4b = fmaxf(t8[1], t8[5]);
  float t4c = fmaxf(t8[2], t8[6]), t4d = fmaxf(t8[3], t8[7]);
  float mx = fmaxf(fmaxf(t4a, t4b), fmaxf(t4c, t4d));
  mx = fmaxf(mx, __shfl_xor(mx, 32));
  bool up = mx > st.mrun + 5.5451774444795624f;  // defer-max, THR=8*ln2
  if (__any(up)) {
    float newm = up ? mx : st.mrun;
    float scl = fexp2((st.mrun - newm) * L2E);
    st.mrun = newm;
    st.lrun *= scl;
#pragma unroll
    for (int r = 0; r < 16; r++) { st.oacc[0][r] *= scl; st.oacc[1][r] *= scl; }
  }
  float nm2 = -st.mrun * L2E;
#pragma unroll
  for (int r = 0; r < 16; r++) {
    sacc[0][r] = fexp2(__builtin_fmaf(sacc[0][r], L2E, nm2));
    sacc[1][r] = fexp2(__builtin_fmaf(sacc[1][r], L2E, nm2));
  }
  float u8[8];
#pragma unroll
  for (int r = 0; r < 8; r++)
    u8[r] = (sacc[0][r] + sacc[0][r + 8]) + (sacc[1][r] + sacc[1][r + 8]);
  st.lrun += ((u8[0] + u8[4]) + (u8[1] + u8[5])) + ((u8[2] + u8[6]) + (u8[3] + u8[7]));
  // P^T -> bf16 B-frags
  u32x4 pa[4];
#pragma unroll
  for (int tau = 0; tau < 2; tau++) {
    u32x2 rA = plswap2(cvtpk(sacc[tau][0], sacc[tau][1]), cvtpk(sacc[tau][4], sacc[tau][5]));
    pa[2 * tau][0] = rA[0]; pa[2 * tau][2] = rA[1];
    u32x2 rC = plswap2(cvtpk(sacc[tau][2], sacc[tau][3]), cvtpk(sacc[tau][6], sacc[tau][7]));
    pa[2 * tau][1] = rC[0]; pa[2 * tau][3] = rC[1];
    u32x2 rA1 = plswap2(cvtpk(sacc[tau][8], sacc[tau][9]), cvtpk(sacc[tau][12], sacc[tau][13]));
    pa[2 * tau + 1][0] = rA1[0]; pa[2 * tau + 1][2] = rA1[1];
    u32x2 rC1 = plswap2(cvtpk(sacc[tau][10], sacc[tau][11]), cvtpk(sacc[tau][14], sacc[tau][15]));
    pa[2 * tau + 1][1] = rC1[0]; pa[2 * tau + 1][3] = rC1[1];
  }
  // O^T += V^T * P^T
  __builtin_amdgcn_s_setprio(1);
#pragma unroll
  for (int kt = 0; kt < 4; kt++) {
    int c = (tb * 8 + ((2 * kt + h) ^ swz)) << 4;
    bf16x8 v0 = *(const bf16x8*)(vbuf + ql * 256 + c);
    bf16x8 v1 = *(const bf16x8*)(vbuf + (32 + ql) * 256 + c);
    bf16x8 pb = __builtin_bit_cast(bf16x8, pa[kt]);
    st.oacc[0] = MFMA32(v0, pb, st.oacc[0]);
    st.oacc[1] = MFMA32(v1, pb, st.oacc[1]);
  }
  __builtin_amdgcn_s_setprio(0);
}

__global__ __launch_bounds__(256) void attn_k(const u16* __restrict__ Q,
                                              const u16* __restrict__ K,
                                              const u16* __restrict__ VT,
                                              u16* __restrict__ O) {
  __shared__ alignas(16) u16 Ks[2][128 * 64];  // [kv][d], swizzled, 16KB each
  __shared__ alignas(16) u16 Vs[2][64 * 128];  // [d][kv], swizzled, 16KB each
  int bh = blockIdx.x;            // fast dim -> bh%8 tracks XCD
  int qc = 15 - (int)blockIdx.y;  // heavy blocks first
  int t = threadIdx.x, w = t >> 6, lane = t & 63;
  int ql = lane & 31, h = lane >> 5;
  size_t base = (size_t)bh * (S_LEN * DHEAD);
  int qrow = qc * 128 + w * 32 + ql;
  bf16x8 qf[4];
#pragma unroll
  for (int kt = 0; kt < 4; kt++)
    qf[kt] = *(const bf16x8*)(Q + base + (size_t)qrow * DHEAD + kt * 16 + h * 8);
  AttnSt st;
  st.oacc[0] = f32x16{};
  st.oacc[1] = f32x16{};
  st.mrun = -1e30f;
  st.lrun = 0.0f;
  // staging source pointers (pre-swizzled global chunks; LDS dest is linear)
  int krow = t >> 3;
  int kc = ((t & 7) ^ (krow & 7)) << 3;  // u16 units
  const u16* Kg0 = K + base + (size_t)krow * DHEAD + kc;
  int vrow = t >> 4;
  int vc = ((t & 15) ^ (vrow & 7)) << 3;  // u16 units
  const u16* Vg0 = VT + (size_t)bh * DHEAD * S_LEN + (size_t)vrow * S_LEN + vc;
  char* klb = (char*)&Ks[0][0] + w * 1024;
  char* vlb = (char*)&Vs[0][0] + w * 1024;

#define STAGE(s, buf)                                                    \
  do {                                                                   \
    int kv0s = (s) * 128;                                                \
    char* kl = klb + (buf) * 16384;                                      \
    char* vl = vlb + (buf) * 16384;                                      \
    _Pragma("unroll")                                                    \
    for (int p = 0; p < 4; p++)                                          \
      gload16(Kg0 + (size_t)(kv0s + p * 32) * DHEAD, kl + p * 4096);     \
    _Pragma("unroll")                                                    \
    for (int p = 0; p < 4; p++)                                          \
      gload16(Vg0 + (size_t)(p * 16) * S_LEN + kv0s, vl + p * 4096);     \
  } while (0)

  STAGE(0, 0);
  asm volatile("s_waitcnt vmcnt(0)" ::: "memory");
  __builtin_amdgcn_s_barrier();
  asm volatile("" ::: "memory");
  int cur = 0;
#pragma unroll 1
  for (int s = 0; s <= qc; ++s) {
    if (s < qc) STAGE(s + 1, cur ^ 1);  // loads in flight across this stage
    const char* kb = (const char*)&Ks[cur][0];
    const char* vb = (const char*)&Vs[cur][0];
    bool diag = (s == qc);
    // tile a: kv [128s, 128s+64)
    attn_tile64(kb, vb, 0, s * 128, diag && (w < 2), qf, qrow, h, ql, st);
    // tile b: kv [128s+64, 128s+128); on diagonal stage waves 0,1 skip it
    if (!(diag && w < 2))
      attn_tile64(kb, vb, 1, s * 128 + 64, diag, qf, qrow, h, ql, st);
    asm volatile("s_waitcnt vmcnt(0)" ::: "memory");
    __builtin_amdgcn_s_barrier();
    asm volatile("" ::: "memory");
    cur ^= 1;
  }
#undef STAGE
  // combine cross-half row-sum, normalize, packed stores
  float lsum = st.lrun + __shfl_xor(st.lrun, 32);
  float inv = 1.0f / lsum;
  int b = bh >> 4, hd = bh & 15;
  u16* Orow = O + ((size_t)(b * S_LEN + qrow)) * DMODEL + hd * 64;
#pragma unroll
  for (int dt = 0; dt < 2; dt++)
#pragma unroll
    for (int rr = 0; rr < 4; rr++) {
      uint2 pk;
      pk.x = cvtpk(st.oacc[dt][4 * rr + 0] * inv, st.oacc[dt][4 * rr + 1] * inv);
      pk.y = cvtpk(st.oacc[dt][4 * rr + 2] * inv, st.oacc[dt][4 * rr + 3] * inv);
      *(uint2*)(Orow + 32 * dt + 8 * rr + 4 * h) = pk;
    }
}

// ---------------- launch -----------------------------------------------------
extern "C" void kernel_launch(void* const* d_in, const int* in_sizes, int n_in,
                              void* d_out, int out_size, void* d_ws, size_t ws_size,
                              hipStream_t stream) {
  (void)in_sizes; (void)n_in; (void)out_size; (void)ws_size;
  const float* x = (const float*)d_in[0];
  const int* tpos = (const int*)d_in[1];
  const float* Wq = (const float*)d_in[2];
  const float* Wk = (const float*)d_in[3];
  const float* Wv = (const float*)d_in[4];
  const float* Wo = (const float*)d_in[5];
  char* ws = (char*)d_ws;
  // workspace map (48 MB used of 56)
  u16* xb  = (u16*)(ws + ((size_t)0 << 20));   // 8 MB  [4096][1024] bf16
  u16* wqb = (u16*)(ws + ((size_t)8 << 20));   // 2 MB
  u16* wkb = (u16*)(ws + ((size_t)10 << 20));  // 2 MB
  u16* wvb = (u16*)(ws + ((size_t)12 << 20));  // 2 MB
  u16* wob = (u16*)(ws + ((size_t)14 << 20));  // 2 MB
  u16* Qb  = (u16*)(ws + ((size_t)16 << 20));  // 8 MB  [B,H,S,DK] (rope'd, scaled)
  u16* Kb  = (u16*)(ws + ((size_t)24 << 20));  // 8 MB  [B,H,S,DK] (rope'd)
  u16* VTb = (u16*)(ws + ((size_t)32 << 20));  // 8 MB  [B,H,DK,S]
  u16* Ob  = (u16*)(ws + ((size_t)40 << 20));  // 8 MB  [B,S,DMODEL] bf16

  convert_k<<<dim3(1024, 8), 256, 0, stream>>>(x, Wq, Wk, Wv, Wo, xb, wqb, wkb, wvb, wob);
  gemm128<1><<<dim3(32, 8, 2), 256, 0, stream>>>(xb, wqb, wkb, (void*)Qb, (void*)Kb, tpos);
  gemm128<2><<<dim3(32, 8, 1), 256, 0, stream>>>(xb, wvb, wvb, (void*)VTb, (void*)VTb, tpos);
  attn_k<<<dim3(32, 16), 256, 0, stream>>>(Qb, Kb, VTb, Ob);
  gemm128<0><<<dim3(32, 8, 1), 256, 0, stream>>>(Ob, wob, wob, d_out, d_out, tpos);
}